// Round 1
// baseline (621.711 us; speedup 1.0000x reference)
//
#include <hip/hip_runtime.h>

// CRF log-likelihood: B=512 sequences, T=1024 steps, K=64 states.
// out = mean_b( Z[b] - gold[b] ), single f32 scalar.
//
// Kernels:
//  1. gold_len_kernel : per-b gold path score + sequence length (1 wave/b)
//  2. fwd_kernel      : per-b forward algorithm -> Z[b]  (1 wave/b, lane=state)
//  3. reduce_kernel   : mean(Z-gold) -> d_out[0]
//
// Key identity: s[k] = h_t[k] + log( sum_j exp(trans[k,j]) * exp(score[j]-gm) ) + gm
// E=exp(trans) hoisted into registers (64 VGPR/lane); inner step = 64 f32 FMA
// with the u-vector broadcast from LDS (ds_read_b128, same-address = conflict-free).
// Score kept normalized (wave-max every 4 steps), offset accumulated in f64 —
// numerically tighter than the reference's raw f32 path.

#define PAD_IDX 0
#define SOS_IDX 1
#define EOS_IDX 2
constexpr float NEGF = -10000.0f;
constexpr int B = 512, T = 1024, K = 64;

// y0 may arrive as int64 (reference dtype) or int32 (JAX default x64-off).
// Little-endian: token values < 2^31, so low word suffices; sh=1 -> stride 2.
__device__ __forceinline__ int yval(const int* __restrict__ y, int i, int sh) {
  return y[i << sh];
}

__global__ __launch_bounds__(64) void gold_len_kernel(
    const float* __restrict__ h, const float* __restrict__ trans,
    const int* __restrict__ y0, double* __restrict__ goldOut,
    int* __restrict__ lenOut)
{
  const int b = blockIdx.x;
  const int lane = threadIdx.x;
  const float* hb = h + (size_t)b * T * K;
  // int64 detection: y0[1] is 0 iff data is int64 (hi word of SOS=1);
  // for int32 data y0[1] = first token >= 3 (len >= T/2 guarantees non-pad).
  const int sh = (y0[1] == 0) ? 1 : 0;
  const int* yb = y0 + (((size_t)b * (T + 1)) << sh);

  double acc = 0.0;
  int maxpos = 0;
  for (int t = lane; t < T; t += 64) {
    int ycur = yval(yb, t + 1, sh);
    if (ycur > PAD_IDX) {                       // mask[t] == 1
      int yprev = yval(yb, t, sh);
      float emit = hb[(size_t)t * K + ycur];
      float tr = trans[ycur * K + yprev];
      acc += (double)(emit + tr);
      maxpos = t + 1;                           // pads are a suffix
    }
  }
  #pragma unroll
  for (int off = 32; off > 0; off >>= 1) {
    acc += __shfl_down(acc, off, 64);
    maxpos = max(maxpos, __shfl_down(maxpos, off, 64));
  }
  if (lane == 0) {
    const int len = maxpos;                     // == mask.sum()
    const int last = yval(yb, len, sh);         // last real token
    acc += (double)trans[EOS_IDX * K + last];
    goldOut[b] = acc;
    lenOut[b] = len;
  }
}

__global__ __launch_bounds__(64) void fwd_kernel(
    const float* __restrict__ h, const float* __restrict__ trans,
    const int* __restrict__ lenIn, double* __restrict__ ZdOut)
{
  __shared__ alignas(16) float u_lds[K];
  const int b = blockIdx.x;
  const int k = threadIdx.x;                    // lane = state index
  const float* hb = h + (size_t)b * T * K;
  const int len = lenIn[b];

  // E row k in registers (fully static indexing -> stays in VGPRs).
  float Er[K];
  #pragma unroll
  for (int j = 0; j < K; ++j) Er[j] = __expf(trans[k * K + j]);

  float sn = (k == SOS_IDX) ? 0.0f : NEGF;      // normalized score
  double O = 0.0;                               // f64 running offset

  auto STEP = [&](float hval) {
    // Single-wave block: DS ops execute in order per wave; no barrier needed.
    u_lds[k] = __expf(sn);
    float v0 = 0.f, v1 = 0.f, v2 = 0.f, v3 = 0.f;
    const float4* u4 = reinterpret_cast<const float4*>(u_lds);
    #pragma unroll
    for (int c = 0; c < 16; ++c) {              // 16x broadcast ds_read_b128
      float4 uu = u4[c];
      v0 = fmaf(Er[4 * c + 0], uu.x, v0);
      v1 = fmaf(Er[4 * c + 1], uu.y, v1);
      v2 = fmaf(Er[4 * c + 2], uu.z, v2);
      v3 = fmaf(Er[4 * c + 3], uu.w, v3);
    }
    sn = __logf((v0 + v1) + (v2 + v3)) + hval;  // log(0)=-inf is benign (SOS/PAD rows)
  };

  auto RENORM = [&]() {                         // every 4 steps: growth ~16 max, exp safe
    float gm = sn;
    #pragma unroll
    for (int off = 32; off > 0; off >>= 1)
      gm = fmaxf(gm, __shfl_xor(gm, off, 64));
    sn -= gm;
    O += (double)gm;
  };

  const int lm1 = len - 1;
  auto hload = [&](int t) { return hb[(size_t)min(t, lm1) * K + k]; };

  // 4-deep h prefetch: loads for t+4..t+7 issue before ~1000cy of compute.
  float p0 = hload(0), p1 = hload(1), p2 = hload(2), p3 = hload(3);
  int t = 0;
  for (; t + 4 <= len; t += 4) {
    float n0 = hload(t + 4), n1 = hload(t + 5), n2 = hload(t + 6), n3 = hload(t + 7);
    STEP(p0); STEP(p1); STEP(p2); STEP(p3);
    RENORM();
    p0 = n0; p1 = n1; p2 = n2; p3 = n3;
  }
  for (; t < len; ++t) STEP(hb[(size_t)t * K + k]);  // <=3 tail steps

  // Z = O + lse_k( sn[k] + trans[EOS,k] )
  float x = sn + trans[EOS_IDX * K + k];
  float m = x;
  #pragma unroll
  for (int off = 32; off > 0; off >>= 1) m = fmaxf(m, __shfl_xor(m, off, 64));
  float e = __expf(x - m);                      // exp(-inf)=0 handles dead states
  float s = e;
  #pragma unroll
  for (int off = 32; off > 0; off >>= 1) s += __shfl_xor(s, off, 64);
  if (k == 0) ZdOut[b] = O + (double)m + (double)__logf(s);
}

__global__ __launch_bounds__(512) void reduce_kernel(
    const double* __restrict__ Zd, const double* __restrict__ goldIn,
    float* __restrict__ out)
{
  __shared__ double sdata[8];
  const int tid = threadIdx.x;
  double v = Zd[tid] - goldIn[tid];
  #pragma unroll
  for (int off = 32; off > 0; off >>= 1) v += __shfl_down(v, off, 64);
  if ((tid & 63) == 0) sdata[tid >> 6] = v;
  __syncthreads();
  if (tid == 0) {
    double s = 0.0;
    #pragma unroll
    for (int i = 0; i < 8; ++i) s += sdata[i];
    out[0] = (float)(s / (double)B);
  }
}

extern "C" void kernel_launch(void* const* d_in, const int* in_sizes, int n_in,
                              void* d_out, int out_size, void* d_ws, size_t ws_size,
                              hipStream_t stream) {
  const float* h = (const float*)d_in[0];
  const float* trans = (const float*)d_in[1];
  const int* y0 = (const int*)d_in[2];   // int32 or int64; detected in-kernel

  double* Zd = (double*)d_ws;            // [B] doubles
  double* gold = Zd + B;                 // [B] doubles
  int* len = (int*)(gold + B);           // [B] ints   (total 10 KB of ws)

  gold_len_kernel<<<B, 64, 0, stream>>>(h, trans, y0, gold, len);
  fwd_kernel<<<B, 64, 0, stream>>>(h, trans, len, Zd);
  reduce_kernel<<<1, 512, 0, stream>>>(Zd, gold, (float*)d_out);
}

// Round 3
// 447.033 us; speedup vs baseline: 1.3907x; 1.3907x over previous
//
#include <hip/hip_runtime.h>

// CRF log-likelihood: B=512, T=1024, K=64. out = mean_b(Z[b]-gold[b]).
//
// Forward recurrence in EXP space to strip transcendentals and shuffle
// reduces off the per-step critical path:
//   u_{t+1}[k] = v[k] * e^{h_t[k]},  v = E u,  E = exp(trans)  (E in 64 VGPR/lane)
// Renorm (divide by v[REFL], readlane + v_rcp, no shuffles) only every 2nd
// step: worst-case growth per step <= e^20, two steps e^40, v <= e^48 << f32
// max e^88.7 -> safe. Offset O accumulates -log(rc) in f64 on a side chain
// (exact bookkeeping: logs the factor actually applied, rcp rounding cancels).
// Critical path/step: ds_write u -> 16x broadcast ds_read_b128 -> 64 FMA
// (8 accs, depth 8) -> [every 2nd: readlane+rcp] -> mul -> ds_write.

#define PAD_IDX 0
#define SOS_IDX 1
#define EOS_IDX 2
constexpr int B = 512, T = 1024, K = 64;
constexpr int REFL = 3;   // renorm reference lane: first live state (0..2 dead/special)

// y0 may be int64 (reference dtype) or int32 (JAX x64-off). Little-endian:
// y0[1]==0 iff int64 (hi word of SOS); int32 data has y0[1]>=3.
__device__ __forceinline__ int yval(const int* __restrict__ y, int i, int sh) {
  return y[i << sh];
}

__global__ __launch_bounds__(256) void gold_len_kernel(
    const float* __restrict__ h, const float* __restrict__ trans,
    const int* __restrict__ y0, double* __restrict__ goldOut,
    int* __restrict__ lenOut)
{
  const int b = blockIdx.x, tid = threadIdx.x;
  const float* hb = h + (size_t)b * T * K;
  const int sh = (y0[1] == 0) ? 1 : 0;
  const int* yb = y0 + (((size_t)b * (T + 1)) << sh);

  double acc = 0.0;
  int maxpos = 0;
  for (int t = tid; t < T; t += 256) {
    int ycur = yval(yb, t + 1, sh);
    if (ycur > PAD_IDX) {                       // mask[t]==1 (pads are a suffix)
      int yprev = yval(yb, t, sh);
      acc += (double)(hb[(size_t)t * K + ycur] + trans[ycur * K + yprev]);
      maxpos = t + 1;
    }
  }
  #pragma unroll
  for (int off = 32; off > 0; off >>= 1) {
    acc += __shfl_down(acc, off, 64);
    maxpos = max(maxpos, __shfl_down(maxpos, off, 64));
  }
  __shared__ double sacc[4];
  __shared__ int smax[4];
  if ((tid & 63) == 0) { sacc[tid >> 6] = acc; smax[tid >> 6] = maxpos; }
  __syncthreads();
  if (tid == 0) {
    double a = (sacc[0] + sacc[1]) + (sacc[2] + sacc[3]);
    int len = max(max(smax[0], smax[1]), max(smax[2], smax[3]));
    int last = yval(yb, len, sh);               // last real token
    a += (double)trans[EOS_IDX * K + last];
    goldOut[b] = a;
    lenOut[b] = len;
  }
}

__global__ __launch_bounds__(64) void fwd_kernel(
    const float* __restrict__ h, const float* __restrict__ trans,
    const int* __restrict__ lenIn, double* __restrict__ ZdOut)
{
  __shared__ alignas(16) float u_lds[K];
  const int b = blockIdx.x;
  const int k = threadIdx.x;                    // lane = state
  const float* hb = h + (size_t)b * T * K;
  const int len = lenIn[b];

  // E row k in registers (static indices -> VGPRs). exp(-10000)=0 reproduces masking.
  float Er[K];
  #pragma unroll
  for (int j = 0; j < K; ++j) Er[j] = __expf(trans[k * K + j]);

  float u = (k == SOS_IDX) ? 1.0f : 0.0f;       // exp-space score (scaled)
  double O = 0.0;                               // f64 log-offset (side chain)

  // One recurrence step; renorm only when RN (every 2nd step -- growth
  // bounded by e^48 between renorms, safe in f32).
  auto STEP = [&](float ehv, bool RN) {
    u_lds[k] = u;                               // single wave: DS ops in order
    const float4* u4 = reinterpret_cast<const float4*>(u_lds);
    float a[8] = {0, 0, 0, 0, 0, 0, 0, 0};      // static idx -> registers
    #pragma unroll
    for (int c = 0; c < 16; ++c) {              // 16x broadcast ds_read_b128
      float4 uu = u4[c];
      a[(4 * c + 0) & 7] = fmaf(Er[4 * c + 0], uu.x, a[(4 * c + 0) & 7]);
      a[(4 * c + 1) & 7] = fmaf(Er[4 * c + 1], uu.y, a[(4 * c + 1) & 7]);
      a[(4 * c + 2) & 7] = fmaf(Er[4 * c + 2], uu.z, a[(4 * c + 2) & 7]);
      a[(4 * c + 3) & 7] = fmaf(Er[4 * c + 3], uu.w, a[(4 * c + 3) & 7]);
    }
    float v = ((a[0] + a[4]) + (a[1] + a[5])) + ((a[2] + a[6]) + (a[3] + a[7]));
    if (RN) {
      // Renorm via live ref lane: readlane (uniform) + raw v_rcp. No shuffles.
      float vr = __uint_as_float(__builtin_amdgcn_readlane(__float_as_uint(v), REFL));
      float rc = __builtin_amdgcn_rcpf(vr);
      O -= (double)__logf(rc);                  // off critical path, exact bookkeeping
      u = v * rc * ehv;
    } else {
      u = v * ehv;
    }
  };

  const int lm1 = len - 1;
  auto hload = [&](int t) { return hb[(size_t)min(t, lm1) * K + k]; };

  // 4-deep prefetch; exp(h) computed off the serial chain.
  float p0 = hload(0), p1 = hload(1), p2 = hload(2), p3 = hload(3);
  int t = 0;
  for (; t + 4 <= len; t += 4) {
    float n0 = hload(t + 4), n1 = hload(t + 5), n2 = hload(t + 6), n3 = hload(t + 7);
    float e0 = __expf(p0), e1 = __expf(p1), e2 = __expf(p2), e3 = __expf(p3);
    STEP(e0, false); STEP(e1, true); STEP(e2, false); STEP(e3, true);
    p0 = n0; p1 = n1; p2 = n2; p3 = n3;
  }
  for (; t < len; ++t) STEP(__expf(hb[(size_t)t * K + k]), true);  // <=3 tail steps

  // Z = O + log( sum_k u[k] * exp(trans[EOS,k]) )   (one-time shuffle reduce)
  float w = u * __expf(trans[EOS_IDX * K + k]);
  #pragma unroll
  for (int off = 32; off > 0; off >>= 1) w += __shfl_xor(w, off, 64);
  if (k == 0) ZdOut[b] = O + (double)__logf(w);
}

__global__ __launch_bounds__(512) void reduce_kernel(
    const double* __restrict__ Zd, const double* __restrict__ goldIn,
    float* __restrict__ out)
{
  __shared__ double sdata[8];
  const int tid = threadIdx.x;
  double v = Zd[tid] - goldIn[tid];
  #pragma unroll
  for (int off = 32; off > 0; off >>= 1) v += __shfl_down(v, off, 64);
  if ((tid & 63) == 0) sdata[tid >> 6] = v;
  __syncthreads();
  if (tid == 0) {
    double s = 0.0;
    #pragma unroll
    for (int i = 0; i < 8; ++i) s += sdata[i];
    out[0] = (float)(s / (double)B);
  }
}

extern "C" void kernel_launch(void* const* d_in, const int* in_sizes, int n_in,
                              void* d_out, int out_size, void* d_ws, size_t ws_size,
                              hipStream_t stream) {
  const float* h = (const float*)d_in[0];
  const float* trans = (const float*)d_in[1];
  const int* y0 = (const int*)d_in[2];   // int32 or int64; detected in-kernel

  double* Zd = (double*)d_ws;            // [B]
  double* gold = Zd + B;                 // [B]
  int* len = (int*)(gold + B);           // [B]

  gold_len_kernel<<<B, 256, 0, stream>>>(h, trans, y0, gold, len);
  fwd_kernel<<<B, 64, 0, stream>>>(h, trans, len, Zd);
  reduce_kernel<<<1, 512, 0, stream>>>(Zd, gold, (float*)d_out);
}